// Round 6
// baseline (891.806 us; speedup 1.0000x reference)
//
#include <hip/hip_runtime.h>
#include <hip/hip_bf16.h>

// B=2, S=128, H=12, DH=64, HID=768
// scores(b,h,i,j) = dot64(q+ra, k+rb)/8 + mask ; t = h*16384+i*128+j ; r=t/12, c=t%12
// ra = ip[r, 64c+d], rb = ip[r, 768+64c+d], ip = inference_path @ Wip (bf16 MFMA, never materialized)
// score_kernel operand order: A = Wip-frags (free dim = d -> C regs), B = ip-rows
// (free dim = row -> C lanes). Epilogue is in-lane over d + one shfl_xor(32).

typedef __attribute__((ext_vector_type(8))) __bf16 bf16x8;
typedef __attribute__((ext_vector_type(4))) __bf16 bf16x4;
typedef __attribute__((ext_vector_type(16))) float f32x16;

// ws layout — total 7,208,960 B (proven footprint)
//   [0)          qkvb  [256][2368] bf16 (q|k|v|pv)            1,212,416
//   [1,212,416)  arena  2304 Wip frags x 1KB                  2,359,296
//   [3,571,712)  arena2 3552 W-qkv frags x 1KB (prep/proj)    3,637,248
//   overlay after proj: scores @3,571,712 (1,572,864), ctx @5,144,576 (851,968)
#define ARENA_OFF 1212416u
#define X_OFF     3571712u
#define CTX_OFF   5144576u

// ---------------- prep: Wip + Wq/Wk/Wv/Wpv fp32 -> bf16 frags ----------------
// frag: lane l holds 8 bf16: col = n32*32+(l&31), k = k16*16+(l>>5)*8+j
__global__ __launch_bounds__(256)
void prep_kernel(const float* __restrict__ Wip, const float* __restrict__ Wq,
                 const float* __restrict__ Wk, const float* __restrict__ Wv,
                 const float* __restrict__ Wpv,
                 __bf16* __restrict__ arena, __bf16* __restrict__ arena2) {
  const int l = threadIdx.x & 63;
  const int f = blockIdx.x * 4 + (threadIdx.x >> 6);   // 0..5855
  const float* src; int ldw, k16, colbase;
  if (f < 2304) {           // Wip: combined ra|rb col space 1536
    int n32 = f / 48; k16 = f - n32 * 48;
    src = Wip; ldw = 1536; colbase = n32 * 32;
  } else {                  // W-qkv: combined col space 2368
    int f2 = f - 2304;
    int n32 = f2 / 48; k16 = f2 - n32 * 48;
    int col = n32 * 32;
    if (col < 768)       { src = Wq;  ldw = 768; colbase = col; }
    else if (col < 1536) { src = Wk;  ldw = 768; colbase = col - 768; }
    else if (col < 2304) { src = Wv;  ldw = 768; colbase = col - 1536; }
    else                 { src = Wpv; ldw = 64;  colbase = col - 2304; }
  }
  const float* p = src + (size_t)(k16 * 16 + (l >> 5) * 8) * ldw + colbase + (l & 31);
  union { __bf16 h[8]; uint4 u; } pk;
#pragma unroll
  for (int j = 0; j < 8; j++) pk.h[j] = (__bf16)p[(size_t)j * ldw];
  if (f < 2304) ((uint4*)arena)[(size_t)f * 64 + l] = pk.u;
  else          ((uint4*)arena2)[(size_t)(f - 2304) * 64 + l] = pk.u;
}

// ---------------- proj: wave-block MFMA, contiguous frag B, bf16 out ----------------
// grid (74 n32, 8 m32) x 64 thr.
__global__ __launch_bounds__(64)
void proj_kernel(const float* __restrict__ hs, const __bf16* __restrict__ arena2,
                 const float* __restrict__ bq, const float* __restrict__ bk,
                 const float* __restrict__ bv, const float* __restrict__ bpv,
                 __bf16* __restrict__ qkvb) {
  const int n0 = blockIdx.x * 32;
  const int m0 = blockIdx.y * 32;
  const int l = threadIdx.x;
  const int rsel = l & 31, ksel = l >> 5;
  const float* bias; int noff;
  if (n0 < 768)       { bias = bq;  noff = n0; }
  else if (n0 < 1536) { bias = bk;  noff = n0 - 768; }
  else if (n0 < 2304) { bias = bv;  noff = n0 - 1536; }
  else                { bias = bpv; noff = n0 - 2304; }
  const uint4* BF = (const uint4*)arena2 + (size_t)blockIdx.x * 48 * 64 + l;
  const float* abase = hs + (size_t)(m0 + rsel) * 768 + ksel * 8;
  f32x16 acc;
#pragma unroll
  for (int z = 0; z < 16; z++) acc[z] = 0.f;

  float4 a0 = *(const float4*)abase;
  float4 a1 = *(const float4*)(abase + 4);
  uint4 bcur = BF[0];
#pragma unroll 1
  for (int k16 = 0; k16 < 48; k16++) {
    float4 na0, na1; uint4 bn;
    if (k16 < 47) {
      const float* np = abase + (k16 + 1) * 16;
      na0 = *(const float4*)np;
      na1 = *(const float4*)(np + 4);
      bn = BF[(k16 + 1) * 64];
    }
    union { __bf16 h[8]; bf16x8 v; } pa;
    pa.h[0] = (__bf16)a0.x; pa.h[1] = (__bf16)a0.y; pa.h[2] = (__bf16)a0.z; pa.h[3] = (__bf16)a0.w;
    pa.h[4] = (__bf16)a1.x; pa.h[5] = (__bf16)a1.y; pa.h[6] = (__bf16)a1.z; pa.h[7] = (__bf16)a1.w;
    acc = __builtin_amdgcn_mfma_f32_32x32x16_bf16(pa.v, *(bf16x8*)&bcur, acc, 0, 0, 0);
    a0 = na0; a1 = na1; bcur = bn;
  }
#pragma unroll
  for (int reg = 0; reg < 16; reg++) {
    int row = (reg & 3) + ((reg >> 2) << 3) + (ksel << 2);
    qkvb[(size_t)(m0 + row) * 2368 + n0 + rsel] = (__bf16)(acc[reg] + bias[noff + rsel]);
  }
}

// ---------------- score: fused ip-GEMM + in-lane score reduction ----------------
extern __shared__ char smem_raw[];

__global__ __launch_bounds__(512, 2)
void score_kernel(const float* __restrict__ infp,
                  const __bf16* __restrict__ arena,
                  const __bf16* __restrict__ qkvb,
                  float* __restrict__ scores) {
  char* Abase = smem_raw;                        // 96 ip frags * 1040 = 99840 B
  const int tid = threadIdx.x;
  const int lane = tid & 63;
  const int rl = lane & 31;      // ip-row within 32 (C col)
  const int kh = lane >> 5;      // k-octet half; also selects d-subset in C regs
  const int wv = tid >> 6;
  const int wc = wv & 3;         // c in {wc, wc+4, wc+8}
  const int ws = wv >> 2;        // row half
  const int blk = blockIdx.x;
  const int b = blk >> 8;
  const int r0 = (blk & 255) << 6;

  // stage A(ip): 64 rows x 768 f32 -> bf16 frag-ordered LDS (HBM read-once)
  {
    const float4* A4 = (const float4*)(infp + (size_t)(b * 16384 + r0) * 768);
#pragma unroll
    for (int p = 0; p < 12; p++) {
      int idx = p * 512 + tid;
      int m = (int)(((unsigned)idx * 10923u) >> 20);   // idx/96
      int g = idx - m * 96;
      float4 v0 = A4[m * 192 + g * 2];
      float4 v1 = A4[m * 192 + g * 2 + 1];
      union { __bf16 h[8]; uint4 u; } pk;
      pk.h[0] = (__bf16)v0.x; pk.h[1] = (__bf16)v0.y;
      pk.h[2] = (__bf16)v0.z; pk.h[3] = (__bf16)v0.w;
      pk.h[4] = (__bf16)v1.x; pk.h[5] = (__bf16)v1.y;
      pk.h[6] = (__bf16)v1.z; pk.h[7] = (__bf16)v1.w;
      int F = (m >> 5) * 48 + (g >> 1);
      int slot = (m & 31) + ((g & 1) << 5);
      *(uint4*)(Abase + ((F * 65 + slot) << 4)) = pk.u;
    }
  }
  __syncthreads();

  const size_t lane_off = (size_t)(lane << 4);
  const uint4* BA = (const uint4*)arena;
  uint4 W0[16], W1[16];          // [ks*4 + {ra_lo, ra_hi, rb_lo, rb_hi}]
  bf16x8 ip0[4], ip1[4];
  f32x16 acc[4];                 // 0=ra_lo 1=rb_lo 2=ra_hi 3=rb_hi

  auto loadW = [&](uint4* dst, int c, int kc) {
    const uint4* pa = BA + (size_t)((2 * c * 48 + kc * 4) * 64) + lane;
#pragma unroll
    for (int ks = 0; ks < 4; ks++) {
      dst[ks * 4 + 0] = pa[ks * 64];            // ra d0..31  (n32 = 2c)
      dst[ks * 4 + 1] = pa[ks * 64 + 3072];     // ra d32..63 (n32 = 2c+1)
      dst[ks * 4 + 2] = pa[ks * 64 + 73728];    // rb d0..31  (n32 = 24+2c)
      dst[ks * 4 + 3] = pa[ks * 64 + 76800];    // rb d32..63 (n32 = 25+2c)
    }
  };
  auto loadIP = [&](bf16x8* dst, int kc) {
#pragma unroll
    for (int ks = 0; ks < 4; ks++)
      dst[ks] = *(const bf16x8*)(Abase + (((ws * 48 + kc * 4 + ks) * 65) << 4) + lane_off);
  };
  auto step = [&](uint4* W, bf16x8* ip) {
#pragma unroll
    for (int ks = 0; ks < 4; ks++) {
      acc[0] = __builtin_amdgcn_mfma_f32_32x32x16_bf16(*(bf16x8*)&W[ks * 4 + 0], ip[ks], acc[0], 0, 0, 0);
      acc[2] = __builtin_amdgcn_mfma_f32_32x32x16_bf16(*(bf16x8*)&W[ks * 4 + 1], ip[ks], acc[2], 0, 0, 0);
      acc[1] = __builtin_amdgcn_mfma_f32_32x32x16_bf16(*(bf16x8*)&W[ks * 4 + 2], ip[ks], acc[1], 0, 0, 0);
      acc[3] = __builtin_amdgcn_mfma_f32_32x32x16_bf16(*(bf16x8*)&W[ks * 4 + 3], ip[ks], acc[3], 0, 0, 0);
    }
  };
  auto epilogue = [&](int c) {
    int row_g = r0 + ws * 32 + rl;
    int t = 12 * row_g + c;
    int hh = t >> 14;
    int ii = (t >> 7) & 127;
    int jj = t & 127;
    const __bf16* qb = qkvb + (size_t)((b << 7) + ii) * 2368 + (hh << 6) + 4 * kh;
    const __bf16* kb = qkvb + (size_t)((b << 7) + jj) * 2368 + 768 + (hh << 6) + 4 * kh;
    bf16x4 qv[8], kv[8];
#pragma unroll
    for (int g = 0; g < 4; g++) {
      qv[g]     = *(const bf16x4*)(qb + g * 8);
      qv[g + 4] = *(const bf16x4*)(qb + 32 + g * 8);
      kv[g]     = *(const bf16x4*)(kb + g * 8);
      kv[g + 4] = *(const bf16x4*)(kb + 32 + g * 8);
    }
    float p = 0.f;
#pragma unroll
    for (int g = 0; g < 4; g++)
#pragma unroll
      for (int e = 0; e < 4; e++) {
        // acc reg r=g*4+e holds d = e + 8g + 4kh (lo) / +32 (hi)
        p += ((float)qv[g][e] + acc[0][g * 4 + e]) * ((float)kv[g][e] + acc[1][g * 4 + e]);
        p += ((float)qv[g + 4][e] + acc[2][g * 4 + e]) * ((float)kv[g + 4][e] + acc[3][g * 4 + e]);
      }
    p += __shfl_xor(p, 32);
    if (kh == 0)
      scores[(size_t)((b * 12 + hh) * 128 + ii) * 128 + jj] = p;
#pragma unroll
    for (int q = 0; q < 4; q++)
#pragma unroll
      for (int z = 0; z < 16; z++) acc[q][z] = 0.f;
  };

#pragma unroll
  for (int q = 0; q < 4; q++)
#pragma unroll
    for (int z = 0; z < 16; z++) acc[q][z] = 0.f;

  loadW(W0, wc, 0);
  loadIP(ip0, 0);
  int kc = 0, c = wc;
#pragma unroll 1
  for (int ith = 0; ith < 18; ith++) {
    // even slot: consume W0/ip0, prefetch W1/ip1 (kc even, never 11)
    {
      int kcn = kc + 1, cn = c;    // even kc+1 <= 11, no wrap
      loadIP(ip1, kcn);
      loadW(W1, cn, kcn);
      __builtin_amdgcn_sched_barrier(0);
      step(W0, ip0);
      kc = kcn; c = cn;
    }
    // odd slot: consume W1/ip1, prefetch W0/ip0; epilogue when kc==11
    {
      int kcn = kc + 1, cn = c;
      if (kcn == 12) { kcn = 0; cn = c + 4; }
      if (kc != 11) {
        loadIP(ip0, kcn);
        loadW(W0, cn, kcn);
        __builtin_amdgcn_sched_barrier(0);
        step(W1, ip1);
      } else {
        step(W1, ip1);
        epilogue(c);
        if (ith < 17) { loadIP(ip0, 0); loadW(W0, cn, 0); }
      }
      kc = kcn; c = cn;
    }
  }
}

// ---------------- attn: one (b,i) per block; softmax 13 rows + PV dots (bf16 v) ----------------
__global__ __launch_bounds__(256)
void attn_kernel(const float* __restrict__ scores, const __bf16* __restrict__ qkvb,
                 const float* __restrict__ mask, const float* __restrict__ span,
                 float* __restrict__ ctx) {
  const int i = blockIdx.x;
  const int b = blockIdx.y;
  const int tid = threadIdx.x;
  const int l = tid & 63;
  const int wvi = tid >> 6;
  __shared__ float w[13][132];
  for (int r = wvi; r < 13; r += 4) {
    if (r < 12) {
      const float* sp = scores + (size_t)((b * 12 + r) * 128 + i) * 128;
      float s0 = sp[l] * 0.125f + mask[b * 128 + l];
      float s1 = sp[l + 64] * 0.125f + mask[b * 128 + l + 64];
      float mx = fmaxf(s0, s1);
#pragma unroll
      for (int o = 32; o; o >>= 1) mx = fmaxf(mx, __shfl_xor(mx, o));
      float e0 = __expf(s0 - mx), e1 = __expf(s1 - mx);
      float sm = e0 + e1;
#pragma unroll
      for (int o = 32; o; o >>= 1) sm += __shfl_xor(sm, o);
      float inv = 1.f / sm;
      w[r][l] = e0 * inv;
      w[r][l + 64] = e1 * inv;
    } else {
      const float* sp = span + (size_t)(b * 128 + i) * 128;
      w[12][l] = sp[l];
      w[12][l + 64] = sp[l + 64];
    }
  }
  __syncthreads();
  for (int o = tid; o < 832; o += 256) {
    int h = o >> 6, d = o & 63;
    const __bf16* vp = qkvb + (size_t)(b * 128) * 2368 + (h < 12 ? 1536 + h * 64 : 2304) + d;
    float acc = 0.f;
#pragma unroll 8
    for (int j = 0; j < 128; j++) acc += w[h][j] * (float)vp[(size_t)j * 2368];
    ctx[(size_t)(b * 128 + i) * 832 + o] = acc;
  }
}

// ---------------- out: wave-block MFMA GEMM, full K, direct stores ----------------
__global__ __launch_bounds__(64)
void out_kernel(const float* __restrict__ ctxb, const float* __restrict__ Wmlp,
                const float* __restrict__ bmlp, float* __restrict__ out) {
  const int n0 = blockIdx.x * 32;
  const int m0 = blockIdx.y * 32;
  const int l = threadIdx.x;
  const int rsel = l & 31, ksel = l >> 5;
  f32x16 acc;
#pragma unroll
  for (int z = 0; z < 16; z++) acc[z] = 0.f;

#pragma unroll 4
  for (int k16 = 0; k16 < 52; k16++) {
    const float* ap = ctxb + (size_t)(m0 + rsel) * 832 + k16 * 16 + ksel * 8;
    float4 a0 = *(const float4*)ap;
    float4 a1 = *(const float4*)(ap + 4);
    union { __bf16 h[8]; bf16x8 v; } pa;
    pa.h[0] = (__bf16)a0.x; pa.h[1] = (__bf16)a0.y; pa.h[2] = (__bf16)a0.z; pa.h[3] = (__bf16)a0.w;
    pa.h[4] = (__bf16)a1.x; pa.h[5] = (__bf16)a1.y; pa.h[6] = (__bf16)a1.z; pa.h[7] = (__bf16)a1.w;
    const float* bp = Wmlp + (size_t)(k16 * 16 + ksel * 8) * 768 + n0 + rsel;
    union { __bf16 h[8]; bf16x8 v; } pb;
#pragma unroll
    for (int j = 0; j < 8; j++) pb.h[j] = (__bf16)bp[(size_t)j * 768];
    acc = __builtin_amdgcn_mfma_f32_32x32x16_bf16(pa.v, pb.v, acc, 0, 0, 0);
  }
#pragma unroll
  for (int reg = 0; reg < 16; reg++) {
    int row = (reg & 3) + ((reg >> 2) << 3) + (ksel << 2);
    out[(size_t)(m0 + row) * 768 + n0 + rsel] = acc[reg] + bmlp[n0 + rsel];
  }
}

// ---------------- launch ----------------
extern "C" void kernel_launch(void* const* d_in, const int* in_sizes, int n_in,
                              void* d_out, int out_size, void* d_ws, size_t ws_size,
                              hipStream_t stream) {
  const float* hs   = (const float*)d_in[0];
  const float* mask = (const float*)d_in[1];
  const float* infp = (const float*)d_in[2];
  const float* span = (const float*)d_in[3];
  const float* Wq   = (const float*)d_in[4];
  const float* bq   = (const float*)d_in[5];
  const float* Wk   = (const float*)d_in[6];
  const float* bk   = (const float*)d_in[7];
  const float* Wv   = (const float*)d_in[8];
  const float* bv   = (const float*)d_in[9];
  const float* Wpv  = (const float*)d_in[10];
  const float* bpv  = (const float*)d_in[11];
  const float* Wip  = (const float*)d_in[12];
  const float* Wmlp = (const float*)d_in[13];
  const float* bmlp = (const float*)d_in[14];
  float* out = (float*)d_out;

  char* ws = (char*)d_ws;
  __bf16* qkvb   = (__bf16*)(ws);
  __bf16* arena  = (__bf16*)(ws + ARENA_OFF);
  __bf16* arena2 = (__bf16*)(ws + X_OFF);       // dead after proj
  float*  scores = (float*)(ws + X_OFF);        // written by score (after proj)
  float*  ctx    = (float*)(ws + CTX_OFF);

  prep_kernel<<<dim3(1464), 256, 0, stream>>>(Wip, Wq, Wk, Wv, Wpv, arena, arena2);
  proj_kernel<<<dim3(74, 8), 64, 0, stream>>>(hs, arena2, bq, bk, bv, bpv, qkvb);
  score_kernel<<<dim3(512), 512, 99840, stream>>>(infp, arena, qkvb, scores);
  attn_kernel<<<dim3(128, 2), 256, 0, stream>>>(scores, qkvb, mask, span, ctx);
  out_kernel<<<dim3(24, 8), 64, 0, stream>>>(ctx, Wmlp, bmlp, out);
}

// Round 7
// 553.867 us; speedup vs baseline: 1.6101x; 1.6101x over previous
//
#include <hip/hip_runtime.h>
#include <hip/hip_bf16.h>

// B=2, S=128, H=12, DH=64, HID=768
// scores(b,h,i,j) = dot64(q+ra, k+rb)/8 + mask ; t = h*16384+i*128+j ; r=t/12, c=t%12
// ra = ip[r, 64c+d], rb = ip[r, 768+64c+d], ip = inference_path @ Wip (bf16 MFMA, never materialized)
// score_kernel operands: A = Wip-frags (free dim = d -> C regs), B = ip-rows (free dim = row -> C lanes).
// Epilogue: in-lane over d + one shfl_xor(32). W dbuf + ip single-buf, epilogue outside inner loop.

typedef __attribute__((ext_vector_type(8))) __bf16 bf16x8;
typedef __attribute__((ext_vector_type(4))) __bf16 bf16x4;
typedef __attribute__((ext_vector_type(16))) float f32x16;

// ws layout — total 7,208,960 B (proven footprint)
//   [0)          qkvb  [256][2368] bf16 (q|k|v|pv)            1,212,416
//   [1,212,416)  arena  2304 Wip frags x 1KB                  2,359,296
//   [3,571,712)  arena2 3552 W-qkv frags x 1KB (prep/proj)    3,637,248
//   overlay after proj: scores @3,571,712 (1,572,864), ctx @5,144,576 (851,968)
#define ARENA_OFF 1212416u
#define X_OFF     3571712u
#define CTX_OFF   5144576u

// ---------------- prep: Wip + Wq/Wk/Wv/Wpv fp32 -> bf16 frags ----------------
// frag: lane l holds 8 bf16: col = n32*32+(l&31), k = k16*16+(l>>5)*8+j
__global__ __launch_bounds__(256)
void prep_kernel(const float* __restrict__ Wip, const float* __restrict__ Wq,
                 const float* __restrict__ Wk, const float* __restrict__ Wv,
                 const float* __restrict__ Wpv,
                 __bf16* __restrict__ arena, __bf16* __restrict__ arena2) {
  const int l = threadIdx.x & 63;
  const int f = blockIdx.x * 4 + (threadIdx.x >> 6);   // 0..5855
  const float* src; int ldw, k16, colbase;
  if (f < 2304) {           // Wip: combined ra|rb col space 1536
    int n32 = f / 48; k16 = f - n32 * 48;
    src = Wip; ldw = 1536; colbase = n32 * 32;
  } else {                  // W-qkv: combined col space 2368
    int f2 = f - 2304;
    int n32 = f2 / 48; k16 = f2 - n32 * 48;
    int col = n32 * 32;
    if (col < 768)       { src = Wq;  ldw = 768; colbase = col; }
    else if (col < 1536) { src = Wk;  ldw = 768; colbase = col - 768; }
    else if (col < 2304) { src = Wv;  ldw = 768; colbase = col - 1536; }
    else                 { src = Wpv; ldw = 64;  colbase = col - 2304; }
  }
  const float* p = src + (size_t)(k16 * 16 + (l >> 5) * 8) * ldw + colbase + (l & 31);
  union { __bf16 h[8]; uint4 u; } pk;
#pragma unroll
  for (int j = 0; j < 8; j++) pk.h[j] = (__bf16)p[(size_t)j * ldw];
  if (f < 2304) ((uint4*)arena)[(size_t)f * 64 + l] = pk.u;
  else          ((uint4*)arena2)[(size_t)(f - 2304) * 64 + l] = pk.u;
}

// ---------------- proj: wave-block MFMA, contiguous frag B, bf16 out ----------------
__global__ __launch_bounds__(64)
void proj_kernel(const float* __restrict__ hs, const __bf16* __restrict__ arena2,
                 const float* __restrict__ bq, const float* __restrict__ bk,
                 const float* __restrict__ bv, const float* __restrict__ bpv,
                 __bf16* __restrict__ qkvb) {
  const int n0 = blockIdx.x * 32;
  const int m0 = blockIdx.y * 32;
  const int l = threadIdx.x;
  const int rsel = l & 31, ksel = l >> 5;
  const float* bias; int noff;
  if (n0 < 768)       { bias = bq;  noff = n0; }
  else if (n0 < 1536) { bias = bk;  noff = n0 - 768; }
  else if (n0 < 2304) { bias = bv;  noff = n0 - 1536; }
  else                { bias = bpv; noff = n0 - 2304; }
  const uint4* BF = (const uint4*)arena2 + (size_t)blockIdx.x * 48 * 64 + l;
  const float* abase = hs + (size_t)(m0 + rsel) * 768 + ksel * 8;
  f32x16 acc;
#pragma unroll
  for (int z = 0; z < 16; z++) acc[z] = 0.f;

  float4 a0 = *(const float4*)abase;
  float4 a1 = *(const float4*)(abase + 4);
  uint4 bcur = BF[0];
#pragma unroll 1
  for (int k16 = 0; k16 < 48; k16++) {
    float4 na0, na1; uint4 bn;
    if (k16 < 47) {
      const float* np = abase + (k16 + 1) * 16;
      na0 = *(const float4*)np;
      na1 = *(const float4*)(np + 4);
      bn = BF[(k16 + 1) * 64];
    }
    union { __bf16 h[8]; bf16x8 v; } pa;
    pa.h[0] = (__bf16)a0.x; pa.h[1] = (__bf16)a0.y; pa.h[2] = (__bf16)a0.z; pa.h[3] = (__bf16)a0.w;
    pa.h[4] = (__bf16)a1.x; pa.h[5] = (__bf16)a1.y; pa.h[6] = (__bf16)a1.z; pa.h[7] = (__bf16)a1.w;
    acc = __builtin_amdgcn_mfma_f32_32x32x16_bf16(pa.v, *(bf16x8*)&bcur, acc, 0, 0, 0);
    a0 = na0; a1 = na1; bcur = bn;
  }
#pragma unroll
  for (int reg = 0; reg < 16; reg++) {
    int row = (reg & 3) + ((reg >> 2) << 3) + (ksel << 2);
    qkvb[(size_t)(m0 + row) * 2368 + n0 + rsel] = (__bf16)(acc[reg] + bias[noff + rsel]);
  }
}

// ---------------- score: fused ip-GEMM + in-lane score reduction ----------------
extern __shared__ char smem_raw[];

__global__ __launch_bounds__(512, 2)
void score_kernel(const float* __restrict__ infp,
                  const __bf16* __restrict__ arena,
                  const __bf16* __restrict__ qkvb,
                  float* __restrict__ scores) {
  char* Abase = smem_raw;                        // 96 ip frags * 1040 = 99840 B
  const int tid = threadIdx.x;
  const int lane = tid & 63;
  const int rl = lane & 31;      // ip-row within 32 (C col)
  const int kh = lane >> 5;      // k-octet half; also selects d-subset in C regs
  const int wv = tid >> 6;
  const int wc = wv & 3;         // c in {wc, wc+4, wc+8}
  const int ws = wv >> 2;        // row half
  const int blk = blockIdx.x;
  const int b = blk >> 8;
  const int r0 = (blk & 255) << 6;

  // stage A(ip): 64 rows x 768 f32 -> bf16 frag-ordered LDS (HBM read-once)
  {
    const float4* A4 = (const float4*)(infp + (size_t)(b * 16384 + r0) * 768);
#pragma unroll
    for (int p = 0; p < 12; p++) {
      int idx = p * 512 + tid;
      int m = (int)(((unsigned)idx * 10923u) >> 20);   // idx/96
      int g = idx - m * 96;
      float4 v0 = A4[m * 192 + g * 2];
      float4 v1 = A4[m * 192 + g * 2 + 1];
      union { __bf16 h[8]; uint4 u; } pk;
      pk.h[0] = (__bf16)v0.x; pk.h[1] = (__bf16)v0.y;
      pk.h[2] = (__bf16)v0.z; pk.h[3] = (__bf16)v0.w;
      pk.h[4] = (__bf16)v1.x; pk.h[5] = (__bf16)v1.y;
      pk.h[6] = (__bf16)v1.z; pk.h[7] = (__bf16)v1.w;
      int F = (m >> 5) * 48 + (g >> 1);
      int slot = (m & 31) + ((g & 1) << 5);
      *(uint4*)(Abase + ((F * 65 + slot) << 4)) = pk.u;
    }
  }
  __syncthreads();

  const size_t lane_off = (size_t)(lane << 4);
  const uint4* BA = (const uint4*)arena;
  uint4 W0[16], W1[16];          // [ks*4 + {ra_lo, ra_hi, rb_lo, rb_hi}]
  bf16x8 ipf[4];
  f32x16 acc[4];                 // 0=ra_lo 1=rb_lo 2=ra_hi 3=rb_hi

  auto loadW = [&](uint4* dst, int c, int kc) {
    const uint4* pa = BA + (size_t)((2 * c * 48 + kc * 4) * 64) + lane;
#pragma unroll
    for (int ks = 0; ks < 4; ks++) {
      dst[ks * 4 + 0] = pa[ks * 64];            // ra d0..31  (n32 = 2c)
      dst[ks * 4 + 1] = pa[ks * 64 + 3072];     // ra d32..63 (n32 = 2c+1)
      dst[ks * 4 + 2] = pa[ks * 64 + 73728];    // rb d0..31  (n32 = 24+2c)
      dst[ks * 4 + 3] = pa[ks * 64 + 76800];    // rb d32..63 (n32 = 25+2c)
    }
  };
  auto loadIP = [&](int kc) {
#pragma unroll
    for (int ks = 0; ks < 4; ks++)
      ipf[ks] = *(const bf16x8*)(Abase + (((ws * 48 + kc * 4 + ks) * 65) << 4) + lane_off);
  };
  auto step = [&](uint4* W) {
#pragma unroll
    for (int ks = 0; ks < 4; ks++) {
      acc[0] = __builtin_amdgcn_mfma_f32_32x32x16_bf16(*(bf16x8*)&W[ks * 4 + 0], ipf[ks], acc[0], 0, 0, 0);
      acc[2] = __builtin_amdgcn_mfma_f32_32x32x16_bf16(*(bf16x8*)&W[ks * 4 + 1], ipf[ks], acc[2], 0, 0, 0);
      acc[1] = __builtin_amdgcn_mfma_f32_32x32x16_bf16(*(bf16x8*)&W[ks * 4 + 2], ipf[ks], acc[1], 0, 0, 0);
      acc[3] = __builtin_amdgcn_mfma_f32_32x32x16_bf16(*(bf16x8*)&W[ks * 4 + 3], ipf[ks], acc[3], 0, 0, 0);
    }
  };

#pragma unroll 1
  for (int ci = 0; ci < 3; ci++) {
    const int c = wc + ci * 4;
#pragma unroll
    for (int q = 0; q < 4; q++)
#pragma unroll
      for (int z = 0; z < 16; z++) acc[q][z] = 0.f;

    loadW(W0, c, 0);
#pragma unroll 1
    for (int kk = 0; kk < 6; kk++) {
      const int kc0 = kk * 2;
      loadW(W1, c, kc0 + 1);
      loadIP(kc0);
      step(W0);
      const int kn = (kk < 5) ? kc0 + 2 : 0;   // kk=5: dummy (reloaded at next ci)
      loadW(W0, c, kn);
      loadIP(kc0 + 1);
      step(W1);
    }

    // epilogue: (q+ra)(k+rb) in-lane over 16 d's per acc pair, one shfl, direct store
    {
      int row_g = r0 + ws * 32 + rl;
      int t = 12 * row_g + c;
      int hh = t >> 14;
      int ii = (t >> 7) & 127;
      int jj = t & 127;
      const __bf16* qb = qkvb + (size_t)((b << 7) + ii) * 2368 + (hh << 6) + 4 * kh;
      const __bf16* kb = qkvb + (size_t)((b << 7) + jj) * 2368 + 768 + (hh << 6) + 4 * kh;
      bf16x4 qv[8], kv[8];
#pragma unroll
      for (int g = 0; g < 4; g++) {
        qv[g]     = *(const bf16x4*)(qb + g * 8);
        qv[g + 4] = *(const bf16x4*)(qb + 32 + g * 8);
        kv[g]     = *(const bf16x4*)(kb + g * 8);
        kv[g + 4] = *(const bf16x4*)(kb + 32 + g * 8);
      }
      float p = 0.f;
#pragma unroll
      for (int g = 0; g < 4; g++)
#pragma unroll
        for (int e = 0; e < 4; e++) {
          p += ((float)qv[g][e] + acc[0][g * 4 + e]) * ((float)kv[g][e] + acc[1][g * 4 + e]);
          p += ((float)qv[g + 4][e] + acc[2][g * 4 + e]) * ((float)kv[g + 4][e] + acc[3][g * 4 + e]);
        }
      p += __shfl_xor(p, 32);
      if (kh == 0)
        scores[(size_t)((b * 12 + hh) * 128 + ii) * 128 + jj] = p;
    }
  }
}

// ---------------- attn: softmax + probs@v, 16 rows per block, V staged in LDS ----------------
__global__ __launch_bounds__(256)
void attn_kernel(const float* __restrict__ scores, const __bf16* __restrict__ qkvb,
                 const float* __restrict__ mask, const float* __restrict__ span,
                 float* __restrict__ ctx) {
  const int h = blockIdx.x;    // 0..12 (12 = parse path)
  const int ig = blockIdx.y;   // 0..7 (16 i each)
  const int b = blockIdx.z;
  const int tid = threadIdx.x;
  __shared__ __bf16 vs[128 * 64];   // V tile [j][d], 16 KB
  __shared__ float w[128];
  __shared__ float red4[4];
  __shared__ float part[256];
  const int voff = (h < 12) ? 1536 + h * 64 : 2304;
  for (int e = tid; e < 8192; e += 256) {
    int jj = e >> 6, dd = e & 63;
    vs[e] = qkvb[(size_t)(b * 128 + jj) * 2368 + voff + dd];
  }
  __syncthreads();
  const int j = tid & 127;
  const int wvi = tid >> 6;
  const int d = tid & 63, q4 = tid >> 6;
  for (int iq = 0; iq < 16; iq++) {
    int i = ig * 16 + iq;
    if (h < 12) {
      float s = scores[(size_t)((b * 12 + h) * 128 + i) * 128 + j] * 0.125f
              + mask[b * 128 + j];
      float mx = s;
#pragma unroll
      for (int o = 32; o; o >>= 1) mx = fmaxf(mx, __shfl_xor(mx, o));
      if ((tid & 63) == 0) red4[wvi] = mx;
      __syncthreads();
      mx = fmaxf(red4[0], red4[1]);
      float e = __expf(s - mx);
      float sm = e;
#pragma unroll
      for (int o = 32; o; o >>= 1) sm += __shfl_xor(sm, o);
      __syncthreads();
      if ((tid & 63) == 0) red4[wvi] = sm;
      __syncthreads();
      sm = red4[0] + red4[1];
      if (tid < 128) w[tid] = e / sm;
    } else {
      if (tid < 128) w[tid] = span[(size_t)(b * 128 + i) * 128 + j];
      __syncthreads();
      __syncthreads();
      __syncthreads();
    }
    __syncthreads();
    float acc = 0.f;
#pragma unroll
    for (int jj = 0; jj < 32; jj++)
      acc += w[q4 * 32 + jj] * (float)vs[(q4 * 32 + jj) * 64 + d];
    part[tid] = acc;
    __syncthreads();
    if (tid < 64)
      ctx[(size_t)(b * 128 + i) * 832 + h * 64 + tid] =
          part[tid] + part[tid + 64] + part[tid + 128] + part[tid + 192];
    __syncthreads();
  }
}

// ---------------- out: wave-block MFMA GEMM, full K, direct stores ----------------
__global__ __launch_bounds__(64)
void out_kernel(const float* __restrict__ ctxb, const float* __restrict__ Wmlp,
                const float* __restrict__ bmlp, float* __restrict__ out) {
  const int n0 = blockIdx.x * 32;
  const int m0 = blockIdx.y * 32;
  const int l = threadIdx.x;
  const int rsel = l & 31, ksel = l >> 5;
  f32x16 acc;
#pragma unroll
  for (int z = 0; z < 16; z++) acc[z] = 0.f;

#pragma unroll 4
  for (int k16 = 0; k16 < 52; k16++) {
    const float* ap = ctxb + (size_t)(m0 + rsel) * 832 + k16 * 16 + ksel * 8;
    float4 a0 = *(const float4*)ap;
    float4 a1 = *(const float4*)(ap + 4);
    union { __bf16 h[8]; bf16x8 v; } pa;
    pa.h[0] = (__bf16)a0.x; pa.h[1] = (__bf16)a0.y; pa.h[2] = (__bf16)a0.z; pa.h[3] = (__bf16)a0.w;
    pa.h[4] = (__bf16)a1.x; pa.h[5] = (__bf16)a1.y; pa.h[6] = (__bf16)a1.z; pa.h[7] = (__bf16)a1.w;
    const float* bp = Wmlp + (size_t)(k16 * 16 + ksel * 8) * 768 + n0 + rsel;
    union { __bf16 h[8]; bf16x8 v; } pb;
#pragma unroll
    for (int j = 0; j < 8; j++) pb.h[j] = (__bf16)bp[(size_t)j * 768];
    acc = __builtin_amdgcn_mfma_f32_32x32x16_bf16(pa.v, pb.v, acc, 0, 0, 0);
  }
#pragma unroll
  for (int reg = 0; reg < 16; reg++) {
    int row = (reg & 3) + ((reg >> 2) << 3) + (ksel << 2);
    out[(size_t)(m0 + row) * 768 + n0 + rsel] = acc[reg] + bmlp[n0 + rsel];
  }
}

// ---------------- launch ----------------
extern "C" void kernel_launch(void* const* d_in, const int* in_sizes, int n_in,
                              void* d_out, int out_size, void* d_ws, size_t ws_size,
                              hipStream_t stream) {
  const float* hs   = (const float*)d_in[0];
  const float* mask = (const float*)d_in[1];
  const float* infp = (const float*)d_in[2];
  const float* span = (const float*)d_in[3];
  const float* Wq   = (const float*)d_in[4];
  const float* bq   = (const float*)d_in[5];
  const float* Wk   = (const float*)d_in[6];
  const float* bk   = (const float*)d_in[7];
  const float* Wv   = (const float*)d_in[8];
  const float* bv   = (const float*)d_in[9];
  const float* Wpv  = (const float*)d_in[10];
  const float* bpv  = (const float*)d_in[11];
  const float* Wip  = (const float*)d_in[12];
  const float* Wmlp = (const float*)d_in[13];
  const float* bmlp = (const float*)d_in[14];
  float* out = (float*)d_out;

  char* ws = (char*)d_ws;
  __bf16* qkvb   = (__bf16*)(ws);
  __bf16* arena  = (__bf16*)(ws + ARENA_OFF);
  __bf16* arena2 = (__bf16*)(ws + X_OFF);       // dead after proj
  float*  scores = (float*)(ws + X_OFF);        // written by score (after proj)
  float*  ctx    = (float*)(ws + CTX_OFF);

  prep_kernel<<<dim3(1464), 256, 0, stream>>>(Wip, Wq, Wk, Wv, Wpv, arena, arena2);
  proj_kernel<<<dim3(74, 8), 64, 0, stream>>>(hs, arena2, bq, bk, bv, bpv, qkvb);
  score_kernel<<<dim3(512), 512, 99840, stream>>>(infp, arena, qkvb, scores);
  attn_kernel<<<dim3(13, 8, 2), 256, 0, stream>>>(scores, qkvb, mask, span, ctx);
  out_kernel<<<dim3(24, 8), 64, 0, stream>>>(ctx, Wmlp, bmlp, out);
}